// Round 6
// baseline (339.692 us; speedup 1.0000x reference)
//
#include <hip/hip_runtime.h>
#include <hip/hip_bf16.h>
#include <math.h>

typedef __bf16 bf16;
typedef __bf16 bf16x4 __attribute__((ext_vector_type(4)));
typedef __bf16 bf16x8 __attribute__((ext_vector_type(8)));
typedef float f32x4 __attribute__((ext_vector_type(4)));
typedef unsigned int u32;
typedef u32 __attribute__((address_space(1))) gu32;
typedef u32 __attribute__((address_space(3))) lu32;

#define TOK   16384
#define D_    256
#define HD    2048
#define VN    2048

#define GLDS16(g, l) __builtin_amdgcn_global_load_lds((gu32*)(g), (lu32*)(l), 16, 0, 0)
// s_waitcnt imm: vmcnt[3:0]|[15:14] | expcnt<<4 | lgkmcnt<<8
#define WAIT_VM(n)  __builtin_amdgcn_s_waitcnt(0x0F70 | (n))   // lgkm=15(no), exp=7(no), vm=n (LITERAL only)
#define WAIT_LGKM0  __builtin_amdgcn_s_waitcnt(0xC07F)          // vm=63(no), exp=7(no), lgkm=0
#define BAR() do { __builtin_amdgcn_s_barrier(); __builtin_amdgcn_sched_barrier(0); } while (0)

// ---------------------------------------------------------------------------
// prep: roles by blockIdx.x. Dtype flag computed block-locally.  (unchanged)
//   b <  4096: convert x
//   b <  4121: biases -> bqkv (WTI-row order), bo -> bob
//   b <  5657: Wq/Wk/Wv transpose into WTI (6144 rows x 256 K):
//              q: row = (d>>4)*256 +       h*16 + (d&15)   (d-block interleave)
//              k: row = (d>>4)*256 + 128 + h*16 + (d&15)
//              v: row = 4096 + d*8 + h                     (d-major)
//   b <  6169: Wo transpose (K permuted d-major) -> WoT
// ---------------------------------------------------------------------------
__device__ __forceinline__ void transpose_body(
    const void* __restrict__ src, bf16* __restrict__ dst, int R, int C,
    int tc, int tr, int f, int mode, float (*tile)[33])
{
    int lx = threadIdx.x & 31, ly = threadIdx.x >> 5;
    for (int i = 0; i < 4; i++) {
        int r = ly + i * 8;
        size_t idx = (size_t)(tr + r) * C + tc + lx;
        tile[r][lx] = f ? ((const float*)src)[idx] : (float)((const bf16*)src)[idx];
    }
    __syncthreads();
    for (int i = 0; i < 4; i++) {
        int r = ly + i * 8;
        int k = tr + lx;                     // source row = K index
        int n = tc + r;                      // source col = output row
        size_t di;
        if (mode == 1)
            di = (size_t)n * 2048 + ((k & 255) << 3) + (k >> 8);
        else if (mode == 2)
            di = (size_t)(4096 + ((n & 255) << 3) + (n >> 8)) * 256 + k;
        else if (mode == 3)
            di = (size_t)((((n & 255) >> 4) << 8) + ((n >> 8) << 4) + (n & 15)) * 256 + k;
        else if (mode == 4)
            di = (size_t)((((n & 255) >> 4) << 8) + 128 + ((n >> 8) << 4) + (n & 15)) * 256 + k;
        else
            di = (size_t)n * R + k;
        dst[di] = (bf16)tile[lx][r];
    }
}

__global__ __launch_bounds__(256) void prep(
    const void* __restrict__ x,
    const void* __restrict__ Wq, const void* __restrict__ bq,
    const void* __restrict__ Wk, const void* __restrict__ bk,
    const void* __restrict__ Wv, const void* __restrict__ bv,
    const void* __restrict__ Wo, const void* __restrict__ bo,
    bf16* __restrict__ xb, bf16* __restrict__ WTI, bf16* __restrict__ WoT,
    bf16* __restrict__ bqkv, bf16* __restrict__ bob)
{
    __shared__ float tile[32][33];
    __shared__ int sflag;
    int tid = threadIdx.x;
    if (tid == 0) sflag = 0;
    __syncthreads();
    {
        float v = fabsf((float)((const bf16*)x)[2 * tid]);
        if (!(v < 1e4f)) sflag = 1;   // benign race, all writers store 1
    }
    __syncthreads();
    int f = sflag;
    int b = blockIdx.x;

    if (b < 4096) {                               // convert x
        int i = b * 256 + tid;
        bf16x4 o;
        if (f) { f32x4 v = ((const f32x4*)x)[i]; for (int e = 0; e < 4; e++) o[e] = (bf16)v[e]; }
        else   { o = ((const bf16x4*)x)[i]; }
        ((bf16x4*)xb)[i] = o;
    } else if (b < 4121) {                        // biases (WTI-row order)
        int i = (b - 4096) * 256 + tid;
        if (i < 6400) {
            const void* src; bf16* dst = bqkv; int off, woff;
            if (i < 2048) {
                src = bq; off = i;
                int d = off & 255, h = off >> 8;
                woff = ((d >> 4) << 8) + (h << 4) + (d & 15);
            } else if (i < 4096) {
                src = bk; off = i - 2048;
                int d = off & 255, h = off >> 8;
                woff = ((d >> 4) << 8) + 128 + (h << 4) + (d & 15);
            } else if (i < 6144) {
                src = bv; off = i - 4096;
                woff = 4096 + ((off & 255) << 3) + (off >> 8);
            } else {
                src = bo; dst = bob; off = i - 6144; woff = off;
            }
            float v = f ? ((const float*)src)[off] : (float)((const bf16*)src)[off];
            dst[woff] = (bf16)v;
        }
        __syncthreads();                          // match transpose barrier count
    } else if (b < 5657) {                        // Wq/Wk/Wv -> WTI
        int idx = b - 4121;                       // 0..1535
        int tx = idx & 63, rest = idx >> 6;
        int ty = rest & 7, tz = rest >> 3;
        const void* src = (tz == 0) ? Wq : (tz == 1) ? Wk : Wv;
        int mode = (tz == 0) ? 3 : (tz == 1) ? 4 : 2;
        transpose_body(src, WTI, 256, 2048, tx * 32, ty * 32, f, mode, tile);
    } else {                                      // Wo -> WoT (K d-major)
        int idx = b - 5657;                       // 0..511
        int tx = idx & 7, ty = idx >> 3;
        transpose_body(Wo, WoT, 2048, 256, tx * 32, ty * 32, f, 1, tile);
    }
}

// ---------------------------------------------------------------------------
// Kernel 1: v = x @ Wv + bv  (d-major cols). Verified round-5 kernel.
// ---------------------------------------------------------------------------
__global__ __launch_bounds__(256) void v_proj(
    const bf16* __restrict__ X, const bf16* __restrict__ WT,
    const bf16* __restrict__ bI, bf16* __restrict__ vout)
{
    __shared__ char smem[36864];               // union: As+Bs (32K) / epi (36K)
    bf16* As = (bf16*)smem;                    // 128*64
    bf16* Bs = (bf16*)(smem + 16384);          // 128*64
    int m0 = blockIdx.y * 128, n0 = blockIdx.x * 128;
    int tid = threadIdx.x, wave = tid >> 6, lane = tid & 63;
    int wm = (wave >> 1) * 64, wn = (wave & 1) * 64;
    int mrow = lane & 15, quad = lane >> 4;
    int lrow8 = lane >> 3, lslot = lane & 7;

    f32x4 acc[4][4] = {};
    for (int k0 = 0; k0 < D_; k0 += 64) {
        __syncthreads();
        for (int i = 0; i < 4; i++) {
            int rbase = wave * 32 + i * 8;
            int row = rbase + lrow8;
            int gc = lslot ^ (row & 7);
            GLDS16(&X[(size_t)(m0 + row) * D_ + k0 + gc * 8], &As[rbase * 64]);
            GLDS16(&WT[(size_t)(n0 + row) * D_ + k0 + gc * 8], &Bs[rbase * 64]);
        }
        __syncthreads();
        for (int kk = 0; kk < 64; kk += 32) {
            int slot = (((kk >> 3) + quad) ^ (mrow & 7)) * 8;
            bf16x8 af[4], bfv[4];
            for (int mt = 0; mt < 4; mt++)
                af[mt] = *(const bf16x8*)&As[(wm + mt * 16 + mrow) * 64 + slot];
            for (int nt = 0; nt < 4; nt++)
                bfv[nt] = *(const bf16x8*)&Bs[(wn + nt * 16 + mrow) * 64 + slot];
            for (int mt = 0; mt < 4; mt++)
                for (int nt = 0; nt < 4; nt++)
                    acc[mt][nt] = __builtin_amdgcn_mfma_f32_16x16x32_bf16(
                        bfv[nt], af[mt], acc[mt][nt], 0, 0, 0);
        }
    }

    __syncthreads();
    bf16* ep = (bf16*)smem + wave * (64 * 72);
    for (int mt = 0; mt < 4; mt++) {
        for (int nt = 0; nt < 4; nt++) {
            int col = n0 + wn + nt * 16 + quad * 4;
            bf16x4 bb = *(const bf16x4*)&bI[col];
            bf16x4 o;
            for (int r = 0; r < 4; r++) o[r] = (bf16)(acc[mt][nt][r] + (float)bb[r]);
            *(bf16x4*)&ep[(mt * 16 + mrow) * 72 + nt * 16 + quad * 4] = o;
        }
    }
    __syncthreads();
    for (int i = 0; i < 8; i++) {
        int r = i * 8 + (lane >> 3);
        int cb = (lane & 7) * 8;
        bf16x8 val = *(const bf16x8*)&ep[r * 72 + cb];
        *(bf16x8*)&vout[(size_t)(m0 + wm + r) * VN + n0 + wn + cb] = val;
    }
}

// ---------------------------------------------------------------------------
// Kernel 2: q/k projection + per-token 8x8 scores + softmax -> P.
// B (WTI) is L2-resident (FETCH 12 MB) -> load it global->VGPR directly
// (bv[ks] = WTI[s*64+brow][(ks*4+quad)*8..], proven identical to the
// Ws-staged fragment by swizzle algebra). NO Ws LDS, NO per-subtile barrier:
// waves free-run; only 16 d-block barriers remain (qkh publish + reuse).
// qkh double-buffered; score dots for d-block j-1 interleave with d-block
// j's MFMAs (VALU pipe || MFMA pipe, same wave). d-block loop is runtime,
// 4 sub-bodies statically unrolled (all S[]/bv[] indices compile-time).
// ---------------------------------------------------------------------------
__global__ __launch_bounds__(512, 2) void qk_score(
    const bf16* __restrict__ X, const bf16* __restrict__ WTI,
    const bf16* __restrict__ bI, float* __restrict__ P)
{
    __shared__ bf16 qkh[2][64 * 256];  // 64 KB; qkh[0] doubles as x-tile staging
    int tid = threadIdx.x, wave = tid >> 6, lane = tid & 63;
    int mrow = lane & 15, quad = lane >> 4;
    int wm3 = (wave >> 2) * 32, wn3 = (wave & 3) * 16;
    int h = lane >> 3, g = lane & 7;
    int t0 = blockIdx.x * 64;

    // ---- prologue: x-tile -> qkh[0] (GLDS16 swizzled), lift areg ----
#pragma unroll
    for (int i = 0; i < 4; i++) {
        int row = (i * 8 + wave) * 2 + (lane >> 5);
        int sl = lane & 31;
        int gc = (sl & 24) | ((sl & 7) ^ (row & 7));
        GLDS16(&X[(size_t)(t0 + row) * 256 + gc * 8], &qkh[0][(i * 8 + wave) * 512]);
    }
    WAIT_VM(0);
    BAR();
    bf16x8 areg[2][8];
#pragma unroll
    for (int mt = 0; mt < 2; mt++)
#pragma unroll
        for (int ks = 0; ks < 8; ks++) {
            int arow = wm3 + mt * 16 + mrow;
            int sl = ks * 4 + quad;
            int ph = (sl & 24) | ((sl & 7) ^ (arow & 7));
            areg[mt][ks] = *(const bf16x8*)&qkh[0][arow * 256 + ph * 8];
        }
    // per-lane B base: row brow=wn3+mrow, col offset quad*8 elems
    const bf16* wbase = WTI + (size_t)(wn3 + mrow) * 256 + quad * 8;
    bf16x8 bvA[8], bvB[8];
#define QK_LOAD(BV, SS) {                                                      \
        const bf16* wp_ = wbase + (size_t)(SS) * 16384;                        \
        _Pragma("unroll")                                                      \
        for (int ks = 0; ks < 8; ks++) BV[ks] = *(const bf16x8*)(wp_ + ks * 32); }
    QK_LOAD(bvA, 0)
    QK_LOAD(bvB, 1)
    WAIT_LGKM0;                        // all waves' areg lifts retired
    BAR();                             // before epi writes reuse qkh[0]

    float S[8] = {};

#define QK_BODY(SUB, BV) {                                                     \
        f32x4 acc0 = {}, acc1 = {};                                            \
        _Pragma("unroll")                                                      \
        for (int ks = 0; ks < 8; ks++) {                                       \
            acc0 = __builtin_amdgcn_mfma_f32_16x16x32_bf16(BV[ks], areg[0][ks], acc0, 0, 0, 0); \
            acc1 = __builtin_amdgcn_mfma_f32_16x16x32_bf16(BV[ks], areg[1][ks], acc1, 0, 0, 0); \
        }                                                                      \
        int s_ = db4 * 4 + (SUB);                                              \
        int hh = ((SUB) & 1) * 4 + (wave & 3);                                 \
        bf16x4 bb = *(const bf16x4*)&bI[s_ * 64 + wn3 + quad * 4];             \
        char* wqk = (char*)qkh[db4 & 1];                                       \
        _Pragma("unroll")                                                      \
        for (int mt = 0; mt < 2; mt++) {                                       \
            int t = wm3 + mt * 16 + mrow;                                      \
            f32x4 a = mt ? acc1 : acc0;                                        \
            bf16x4 o;                                                          \
            for (int r = 0; r < 4; r++) o[r] = (bf16)(a[r] + (float)bb[r]);    \
            int bo = ((((SUB) >> 1) << 8) + (hh << 5) + (quad << 3)) ^ ((t & 7) << 4); \
            *(bf16x4*)(wqk + t * 512 + bo) = o;                                \
        }                                                                      \
        if (db4 > 0) {                                                         \
            const char* sb = (const char*)qkh[(db4 & 1) ^ 1];                  \
            _Pragma("unroll")                                                  \
            for (int u = 0; u < 2; u++) {                                      \
                int tt = (SUB) * 2 + u;                                        \
                int t = wave * 8 + tt;                                         \
                int swz = (t & 7) << 4;                                        \
                const char* base = sb + t * 512;                               \
                bf16x8 q0 = *(const bf16x8*)(base + ((h << 5) ^ swz));         \
                bf16x8 q1 = *(const bf16x8*)(base + (((h << 5) + 16) ^ swz));  \
                bf16x8 k0 = *(const bf16x8*)(base + ((256 + (g << 5)) ^ swz)); \
                bf16x8 k1 = *(const bf16x8*)(base + ((256 + (g << 5) + 16) ^ swz)); \
                float a = 0.f;                                                 \
                _Pragma("unroll")                                              \
                for (int e = 0; e < 8; e++)                                    \
                    a += (float)q0[e] * (float)k0[e] + (float)q1[e] * (float)k1[e]; \
                S[tt] += a;                                                    \
            }                                                                  \
        }                                                                      \
    }

    for (int db4 = 0; db4 < 16; db4++) {
        QK_BODY(0, bvA)
        QK_LOAD(bvA, db4 * 4 + 2)
        QK_BODY(1, bvB)
        QK_LOAD(bvB, db4 * 4 + 3)
        QK_BODY(2, bvA)
        if (db4 < 15) QK_LOAD(bvA, db4 * 4 + 4)
        QK_BODY(3, bvB)
        if (db4 < 15) QK_LOAD(bvB, db4 * 4 + 5)
        WAIT_LGKM0;                    // epi writes committed + score reads retired
        BAR();                         // publish d-block db4; guard qkh reuse
    }
#undef QK_BODY
#undef QK_LOAD

    // ---- scores for final d-block (15, buffer 1) ----
    {
        const char* sb = (const char*)qkh[1];
#pragma unroll
        for (int tt = 0; tt < 8; tt++) {
            int t = wave * 8 + tt;
            int swz = (t & 7) << 4;
            const char* base = sb + t * 512;
            bf16x8 q0 = *(const bf16x8*)(base + ((h << 5) ^ swz));
            bf16x8 q1 = *(const bf16x8*)(base + (((h << 5) + 16) ^ swz));
            bf16x8 k0 = *(const bf16x8*)(base + ((256 + (g << 5)) ^ swz));
            bf16x8 k1 = *(const bf16x8*)(base + ((256 + (g << 5) + 16) ^ swz));
            float a = 0.f;
#pragma unroll
            for (int e = 0; e < 8; e++)
                a += (float)q0[e] * (float)k0[e] + (float)q1[e] * (float)k1[e];
            S[tt] += a;
        }
    }

    // ---- softmax + P write (wave owns tokens wave*8..+7) ----
#pragma unroll
    for (int ti = 0; ti < 8; ti++) {
        int t = t0 + wave * 8 + ti;
        float sc = S[ti] * 0.0625f;
        float m = sc;
        for (int off = 1; off < 8; off <<= 1) m = fmaxf(m, __shfl_xor(m, off, 8));
        float p = __expf(sc - m);
        float sum = p;
        for (int off = 1; off < 8; off <<= 1) sum += __shfl_xor(sum, off, 8);
        P[(size_t)t * 64 + lane] = p / sum;
    }
}

// ---------------------------------------------------------------------------
// Kernel 3: out = (P @ v) @ Wo' + bo, attnout never in LDS or HBM.
// (Verified round-5 kernel, unchanged.)
// ---------------------------------------------------------------------------
__global__ __launch_bounds__(256) void out_fused(
    const bf16* __restrict__ vb, const bf16* __restrict__ WoT,
    const float* __restrict__ P, const bf16* __restrict__ bob,
    float* __restrict__ outp)
{
    __shared__ bf16 Bs[2][256 * 64];   // 64 KB  Wo' chunk (double)
    __shared__ bf16 Vs[2][32 * 64];    // 8 KB   v chunk (double)
    int m0 = blockIdx.x * 32;
    int tid = threadIdx.x, wave = tid >> 6, lane = tid & 63;
    int wm = (wave >> 1) * 16, wn = (wave & 1) * 128;
    int mrow = lane & 15, quad = lane >> 4;
    int t = wm + mrow, ts = t & 7;
    int sl8 = lane >> 3, sl = lane & 7;

    float Pv[64];
    {
        const float* pr = P + (size_t)(m0 + t) * 64;
#pragma unroll
        for (int j = 0; j < 16; j++) {
            f32x4 v4 = *(const f32x4*)&pr[j * 4];
            Pv[4 * j + 0] = v4[0]; Pv[4 * j + 1] = v4[1];
            Pv[4 * j + 2] = v4[2]; Pv[4 * j + 3] = v4[3];
        }
    }

    f32x4 acc[8] = {};
    {   // prologue: stage chunk 0
        int tt = (wave << 3) + sl8;
        GLDS16(&vb[(size_t)(m0 + tt) * VN + ((sl ^ (tt & 7)) << 3)],
               &Vs[0][wave * 512]);
#pragma unroll
        for (int i = 0; i < 8; i++) {
            int n = (wave << 6) + (i << 3) + sl8;
            GLDS16(&WoT[(size_t)n * HD + ((sl ^ (n & 7)) << 3)],
                   &Bs[0][((wave << 6) + (i << 3)) << 6]);
        }
    }

    for (int c = 0; c < 32; c++) {
        __syncthreads();               // buf[c&1] resident (barrier drains vmcnt)
        if (c < 31) {
            int cc = c + 1, bb = cc & 1;
            int tt = (wave << 3) + sl8;
            GLDS16(&vb[(size_t)(m0 + tt) * VN + cc * 64 + ((sl ^ (tt & 7)) << 3)],
                   &Vs[bb][wave * 512]);
#pragma unroll
            for (int i = 0; i < 8; i++) {
                int n = (wave << 6) + (i << 3) + sl8;
                GLDS16(&WoT[(size_t)n * HD + cc * 64 + ((sl ^ (n & 7)) << 3)],
                       &Bs[bb][((wave << 6) + (i << 3)) << 6]);
            }
        }
        const bf16* Vb = Vs[c & 1];
        const bf16* Bb = Bs[c & 1];

        bf16x8 vf0 = *(const bf16x8*)&Vb[(t << 6) + ((quad ^ ts) << 3)];
        bf16x8 vf1 = *(const bf16x8*)&Vb[(t << 6) + (((quad + 4) ^ ts) << 3)];
        float v0f[8], v1f[8];
#pragma unroll
        for (int e = 0; e < 8; e++) { v0f[e] = (float)vf0[e]; v1f[e] = (float)vf1[e]; }
        bf16x8 af0, af1;
#pragma unroll
        for (int hh = 0; hh < 8; hh++) {
            float a0 = 0.f, a1 = 0.f;
#pragma unroll
            for (int gg = 0; gg < 8; gg++) {
                a0 += Pv[hh * 8 + gg] * v0f[gg];
                a1 += Pv[hh * 8 + gg] * v1f[gg];
            }
            af0[hh] = (bf16)a0; af1[hh] = (bf16)a1;
        }
#pragma unroll
        for (int nt = 0; nt < 8; nt++) {
            bf16x8 bv = *(const bf16x8*)&Bb[(wn + nt * 16 + mrow) * 64
                            + ((quad ^ (mrow & 7)) << 3)];
            acc[nt] = __builtin_amdgcn_mfma_f32_16x16x32_bf16(bv, af0, acc[nt], 0, 0, 0);
        }
#pragma unroll
        for (int nt = 0; nt < 8; nt++) {
            bf16x8 bv = *(const bf16x8*)&Bb[(wn + nt * 16 + mrow) * 64
                            + (((4 + quad) ^ (mrow & 7)) << 3)];
            acc[nt] = __builtin_amdgcn_mfma_f32_16x16x32_bf16(bv, af1, acc[nt], 0, 0, 0);
        }
    }

    int row = m0 + wm + mrow;
#pragma unroll
    for (int nt = 0; nt < 8; nt++) {
        int col = wn + nt * 16 + quad * 4;
        bf16x4 bb = *(const bf16x4*)&bob[col];
        f32x4 o;
        for (int r = 0; r < 4; r++) o[r] = acc[nt][r] + (float)bb[r];
        *(f32x4*)&outp[(size_t)row * D_ + col] = o;
    }
}

// ---------------------------------------------------------------------------
extern "C" void kernel_launch(void* const* d_in, const int* in_sizes, int n_in,
                              void* d_out, int out_size, void* d_ws, size_t ws_size,
                              hipStream_t stream)
{
    const void* x  = d_in[0];
    const void* Wq = d_in[1];
    const void* bq = d_in[2];
    const void* Wk = d_in[3];
    const void* bk = d_in[4];
    const void* Wv = d_in[5];
    const void* bv = d_in[6];
    const void* Wo = d_in[7];
    const void* bo = d_in[8];
    float* out = (float*)d_out;

    char* ws = (char*)d_ws;
    bf16*  vbuf = (bf16*)ws;                      // 16384*2048*2 = 67108864
    bf16*  WTI  = (bf16*)(ws + 67108864);         // 6144*256*2   = 3145728
    bf16*  WoT  = (bf16*)(ws + 70254592);         // 256*2048*2   = 1048576
    bf16*  xb   = (bf16*)(ws + 71303168);         // 16384*256*2  = 8388608
    bf16*  bqkv = (bf16*)(ws + 79691776);         // 6144*2       = 12288
    bf16*  bob  = (bf16*)(ws + 79704064);         // 512
    float* Pbuf = (float*)(ws + 79704576);        // 16384*64*4   = 4194304

    prep<<<6169, 256, 0, stream>>>(x, Wq, bq, Wk, bk, Wv, bv, Wo, bo,
                                   xb, WTI, WoT, bqkv, bob);
    qk_score<<<256, 512, 0, stream>>>(xb, WTI, bqkv, Pbuf);
    v_proj<<<dim3(16, 128), 256, 0, stream>>>(xb, WTI + 4096 * 256, bqkv + 4096, vbuf);
    out_fused<<<512, 256, 0, stream>>>(vbuf, WoT, Pbuf, bob, out);
}

// Round 7
// 264.478 us; speedup vs baseline: 1.2844x; 1.2844x over previous
//
#include <hip/hip_runtime.h>
#include <hip/hip_bf16.h>
#include <math.h>

typedef __bf16 bf16;
typedef __bf16 bf16x4 __attribute__((ext_vector_type(4)));
typedef __bf16 bf16x8 __attribute__((ext_vector_type(8)));
typedef float f32x4 __attribute__((ext_vector_type(4)));
typedef unsigned int u32;
typedef u32 __attribute__((address_space(1))) gu32;
typedef u32 __attribute__((address_space(3))) lu32;

#define TOK   16384
#define D_    256
#define HD    2048
#define VN    2048

#define GLDS16(g, l) __builtin_amdgcn_global_load_lds((gu32*)(g), (lu32*)(l), 16, 0, 0)
#define WAIT_LGKM0  __builtin_amdgcn_s_waitcnt(0xC07F)          // vm=63(no), exp=7(no), lgkm=0
#define BAR() do { __builtin_amdgcn_s_barrier(); __builtin_amdgcn_sched_barrier(0); } while (0)

// ---------------------------------------------------------------------------
// prep: roles by blockIdx.x. Dtype flag computed block-locally.  (unchanged)
//   b <  4096: convert x
//   b <  4121: biases -> bqkv (WTI-row order), bo -> bob
//   b <  5657: Wq/Wk/Wv transpose into WTI (6144 rows x 256 K):
//              q: row = (d>>4)*256 +       h*16 + (d&15)   (d-block interleave)
//              k: row = (d>>4)*256 + 128 + h*16 + (d&15)
//              v: row = 4096 + d*8 + h                     (d-major)
//   b <  6169: Wo transpose (K permuted d-major) -> WoT
// ---------------------------------------------------------------------------
__device__ __forceinline__ void transpose_body(
    const void* __restrict__ src, bf16* __restrict__ dst, int R, int C,
    int tc, int tr, int f, int mode, float (*tile)[33])
{
    int lx = threadIdx.x & 31, ly = threadIdx.x >> 5;
    for (int i = 0; i < 4; i++) {
        int r = ly + i * 8;
        size_t idx = (size_t)(tr + r) * C + tc + lx;
        tile[r][lx] = f ? ((const float*)src)[idx] : (float)((const bf16*)src)[idx];
    }
    __syncthreads();
    for (int i = 0; i < 4; i++) {
        int r = ly + i * 8;
        int k = tr + lx;                     // source row = K index
        int n = tc + r;                      // source col = output row
        size_t di;
        if (mode == 1)
            di = (size_t)n * 2048 + ((k & 255) << 3) + (k >> 8);
        else if (mode == 2)
            di = (size_t)(4096 + ((n & 255) << 3) + (n >> 8)) * 256 + k;
        else if (mode == 3)
            di = (size_t)((((n & 255) >> 4) << 8) + ((n >> 8) << 4) + (n & 15)) * 256 + k;
        else if (mode == 4)
            di = (size_t)((((n & 255) >> 4) << 8) + 128 + ((n >> 8) << 4) + (n & 15)) * 256 + k;
        else
            di = (size_t)n * R + k;
        dst[di] = (bf16)tile[lx][r];
    }
}

__global__ __launch_bounds__(256) void prep(
    const void* __restrict__ x,
    const void* __restrict__ Wq, const void* __restrict__ bq,
    const void* __restrict__ Wk, const void* __restrict__ bk,
    const void* __restrict__ Wv, const void* __restrict__ bv,
    const void* __restrict__ Wo, const void* __restrict__ bo,
    bf16* __restrict__ xb, bf16* __restrict__ WTI, bf16* __restrict__ WoT,
    bf16* __restrict__ bqkv, bf16* __restrict__ bob)
{
    __shared__ float tile[32][33];
    __shared__ int sflag;
    int tid = threadIdx.x;
    if (tid == 0) sflag = 0;
    __syncthreads();
    {
        float v = fabsf((float)((const bf16*)x)[2 * tid]);
        if (!(v < 1e4f)) sflag = 1;   // benign race, all writers store 1
    }
    __syncthreads();
    int f = sflag;
    int b = blockIdx.x;

    if (b < 4096) {                               // convert x
        int i = b * 256 + tid;
        bf16x4 o;
        if (f) { f32x4 v = ((const f32x4*)x)[i]; for (int e = 0; e < 4; e++) o[e] = (bf16)v[e]; }
        else   { o = ((const bf16x4*)x)[i]; }
        ((bf16x4*)xb)[i] = o;
    } else if (b < 4121) {                        // biases (WTI-row order)
        int i = (b - 4096) * 256 + tid;
        if (i < 6400) {
            const void* src; bf16* dst = bqkv; int off, woff;
            if (i < 2048) {
                src = bq; off = i;
                int d = off & 255, h = off >> 8;
                woff = ((d >> 4) << 8) + (h << 4) + (d & 15);
            } else if (i < 4096) {
                src = bk; off = i - 2048;
                int d = off & 255, h = off >> 8;
                woff = ((d >> 4) << 8) + 128 + (h << 4) + (d & 15);
            } else if (i < 6144) {
                src = bv; off = i - 4096;
                woff = 4096 + ((off & 255) << 3) + (off >> 8);
            } else {
                src = bo; dst = bob; off = i - 6144; woff = off;
            }
            float v = f ? ((const float*)src)[off] : (float)((const bf16*)src)[off];
            dst[woff] = (bf16)v;
        }
        __syncthreads();                          // match transpose barrier count
    } else if (b < 5657) {                        // Wq/Wk/Wv -> WTI
        int idx = b - 4121;                       // 0..1535
        int tx = idx & 63, rest = idx >> 6;
        int ty = rest & 7, tz = rest >> 3;
        const void* src = (tz == 0) ? Wq : (tz == 1) ? Wk : Wv;
        int mode = (tz == 0) ? 3 : (tz == 1) ? 4 : 2;
        transpose_body(src, WTI, 256, 2048, tx * 32, ty * 32, f, mode, tile);
    } else {                                      // Wo -> WoT (K d-major)
        int idx = b - 5657;                       // 0..511
        int tx = idx & 7, ty = idx >> 3;
        transpose_body(Wo, WoT, 2048, 256, tx * 32, ty * 32, f, 1, tile);
    }
}

// ---------------------------------------------------------------------------
// Kernel 1: v = x @ Wv + bv  (d-major cols). Verified kernel, unchanged.
// ---------------------------------------------------------------------------
__global__ __launch_bounds__(256) void v_proj(
    const bf16* __restrict__ X, const bf16* __restrict__ WT,
    const bf16* __restrict__ bI, bf16* __restrict__ vout)
{
    __shared__ char smem[36864];               // union: As+Bs (32K) / epi (36K)
    bf16* As = (bf16*)smem;                    // 128*64
    bf16* Bs = (bf16*)(smem + 16384);          // 128*64
    int m0 = blockIdx.y * 128, n0 = blockIdx.x * 128;
    int tid = threadIdx.x, wave = tid >> 6, lane = tid & 63;
    int wm = (wave >> 1) * 64, wn = (wave & 1) * 64;
    int mrow = lane & 15, quad = lane >> 4;
    int lrow8 = lane >> 3, lslot = lane & 7;

    f32x4 acc[4][4] = {};
    for (int k0 = 0; k0 < D_; k0 += 64) {
        __syncthreads();
        for (int i = 0; i < 4; i++) {
            int rbase = wave * 32 + i * 8;
            int row = rbase + lrow8;
            int gc = lslot ^ (row & 7);
            GLDS16(&X[(size_t)(m0 + row) * D_ + k0 + gc * 8], &As[rbase * 64]);
            GLDS16(&WT[(size_t)(n0 + row) * D_ + k0 + gc * 8], &Bs[rbase * 64]);
        }
        __syncthreads();
        for (int kk = 0; kk < 64; kk += 32) {
            int slot = (((kk >> 3) + quad) ^ (mrow & 7)) * 8;
            bf16x8 af[4], bfv[4];
            for (int mt = 0; mt < 4; mt++)
                af[mt] = *(const bf16x8*)&As[(wm + mt * 16 + mrow) * 64 + slot];
            for (int nt = 0; nt < 4; nt++)
                bfv[nt] = *(const bf16x8*)&Bs[(wn + nt * 16 + mrow) * 64 + slot];
            for (int mt = 0; mt < 4; mt++)
                for (int nt = 0; nt < 4; nt++)
                    acc[mt][nt] = __builtin_amdgcn_mfma_f32_16x16x32_bf16(
                        bfv[nt], af[mt], acc[mt][nt], 0, 0, 0);
        }
    }

    __syncthreads();
    bf16* ep = (bf16*)smem + wave * (64 * 72);
    for (int mt = 0; mt < 4; mt++) {
        for (int nt = 0; nt < 4; nt++) {
            int col = n0 + wn + nt * 16 + quad * 4;
            bf16x4 bb = *(const bf16x4*)&bI[col];
            bf16x4 o;
            for (int r = 0; r < 4; r++) o[r] = (bf16)(acc[mt][nt][r] + (float)bb[r]);
            *(bf16x4*)&ep[(mt * 16 + mrow) * 72 + nt * 16 + quad * 4] = o;
        }
    }
    __syncthreads();
    for (int i = 0; i < 8; i++) {
        int r = i * 8 + (lane >> 3);
        int cb = (lane & 7) * 8;
        bf16x8 val = *(const bf16x8*)&ep[r * 72 + cb];
        *(bf16x8*)&vout[(size_t)(m0 + wm + r) * VN + n0 + wn + cb] = val;
    }
}

// ---------------------------------------------------------------------------
// Kernel 2: q/k projection + per-token 8x8 scores + softmax -> P.
// v3: proj_gemm sync pattern (single-buffer Ws, 2 __syncthreads/subtile) at
// 32 tokens/block, grid 512 -> 2 anti-phase blocks/CU (LDS 48 KB), 16
// waves/CU. Round-5 arithmetic verbatim; qkh swizzle extended with
// ^(h&4)<<2 on write AND read (spreads h/h+4, g/g+4 across all 32 banks).
// ---------------------------------------------------------------------------
__global__ __launch_bounds__(512, 4) void qk_score(
    const bf16* __restrict__ X, const bf16* __restrict__ WTI,
    const bf16* __restrict__ bI, float* __restrict__ P)
{
    __shared__ bf16 Ws[64 * 256];      // 32 KB  W subtile (single buffer)
    __shared__ bf16 qkh[32 * 256];     // 16 KB  [t][qk*128+h*16+dd] swizzled;
                                       //        doubles as x-tile at prologue
    int tid = threadIdx.x, wave = tid >> 6, lane = tid & 63;
    int mrow = lane & 15, quad = lane >> 4;
    int wm3 = (wave >> 2) * 16, wn3 = (wave & 3) * 16;
    int h = lane >> 3, g = lane & 7;
    int hx = (h & 4) << 2, gx = (g & 4) << 2;
    int t0 = blockIdx.x * 32;

    // ---- prologue: x-tile (32x256) -> qkh, lift areg ----
#pragma unroll
    for (int i = 0; i < 2; i++) {
        int row = i * 16 + wave * 2 + (lane >> 5);
        int sl = lane & 31;
        int gc = (sl & 24) | ((sl & 7) ^ (row & 7));
        GLDS16(&X[(size_t)(t0 + row) * 256 + gc * 8], &qkh[(i * 16 + wave * 2) * 256]);
    }
    __syncthreads();                   // x-tile resident (drains vmcnt)
    bf16x8 areg[8];
#pragma unroll
    for (int ks = 0; ks < 8; ks++) {
        int arow = wm3 + mrow;
        int sl = ks * 4 + quad;
        int ph = (sl & 24) | ((sl & 7) ^ (arow & 7));
        areg[ks] = *(const bf16x8*)&qkh[arow * 256 + ph * 8];
    }
    WAIT_LGKM0;                        // A lifts retired before qkh reused
    BAR();

    float S[4] = {};

    for (int s = 0; s < 64; s++) {
        __syncthreads();               // (A) Ws readers + score readers done
#pragma unroll
        for (int i = 0; i < 4; i++) {  // stage Ws <- WTI subtile s
            int row = (i * 8 + wave) * 2 + (lane >> 5);
            int sl = lane & 31;
            int gc = (sl & 24) | ((sl & 7) ^ (row & 7));
            GLDS16(&WTI[(size_t)(s * 64 + row) * 256 + gc * 8],
                   &Ws[(i * 8 + wave) * 512]);
        }
        __syncthreads();               // (B) Ws resident (drains vmcnt)

        // GEMM: wave -> rows wm3..+15, cols wn3..+15 (8 MFMA)
        int brow = wn3 + mrow;
        bf16x8 bv[8];
#pragma unroll
        for (int ks = 0; ks < 8; ks++) {
            int sl = ks * 4 + quad;
            int ph = (sl & 24) | ((sl & 7) ^ (brow & 7));
            bv[ks] = *(const bf16x8*)&Ws[brow * 256 + ph * 8];
        }
        f32x4 acc = {};
#pragma unroll
        for (int ks = 0; ks < 8; ks++)
            acc = __builtin_amdgcn_mfma_f32_16x16x32_bf16(bv[ks], areg[ks], acc, 0, 0, 0);

        // epilogue -> qkh (bias added; token-XOR + head-bank XOR)
        int sub = s & 3, qk = sub >> 1;
        int hh = (sub & 1) * 4 + (wave & 3);
        bf16x4 bb = *(const bf16x4*)&bI[s * 64 + wn3 + quad * 4];
        {
            int t = wm3 + mrow;
            bf16x4 o;
#pragma unroll
            for (int r = 0; r < 4; r++) o[r] = (bf16)(acc[r] + (float)bb[r]);
            int bo = (((qk << 8) + (hh << 5) + (quad << 3))
                      ^ ((t & 7) << 4)) ^ ((sub & 1) << 4);
            *(bf16x4*)((char*)qkh + t * 512 + bo) = o;
        }

        if (sub == 3) {                // d-block complete: accumulate scores
            WAIT_LGKM0;                // my epi writes committed
            BAR();                     // everyone's epi writes visible
#pragma unroll
            for (int u = 0; u < 4; u++) {
                int t = wave * 4 + u;
                int swz = (t & 7) << 4;
                const char* base = (const char*)qkh + t * 512;
                bf16x8 q0 = *(const bf16x8*)(base + ((((h << 5)) ^ hx) ^ swz));
                bf16x8 q1 = *(const bf16x8*)(base + ((((h << 5) + 16) ^ hx) ^ swz));
                bf16x8 k0 = *(const bf16x8*)(base + (256 + ((((g << 5)) ^ gx) ^ swz)));
                bf16x8 k1 = *(const bf16x8*)(base + (256 + ((((g << 5) + 16) ^ gx) ^ swz)));
                float a = 0.f;
#pragma unroll
                for (int e = 0; e < 8; e++)
                    a += (float)q0[e] * (float)k0[e] + (float)q1[e] * (float)k1[e];
                S[u] += a;
            }
            WAIT_LGKM0;                // my score reads retired before next
        }                              // group's writers pass barrier (A)
    }

    // ---- softmax + P write (wave owns tokens wave*4..+3) ----
#pragma unroll
    for (int ti = 0; ti < 4; ti++) {
        int t = t0 + wave * 4 + ti;
        float sc = S[ti] * 0.0625f;
        float m = sc;
        for (int off = 1; off < 8; off <<= 1) m = fmaxf(m, __shfl_xor(m, off, 8));
        float p = __expf(sc - m);
        float sum = p;
        for (int off = 1; off < 8; off <<= 1) sum += __shfl_xor(sum, off, 8);
        P[(size_t)t * 64 + lane] = p / sum;
    }
}

// ---------------------------------------------------------------------------
// Kernel 3: out = (P @ v) @ Wo' + bo, attnout never in LDS or HBM.
// (Verified kernel, unchanged.)
// ---------------------------------------------------------------------------
__global__ __launch_bounds__(256) void out_fused(
    const bf16* __restrict__ vb, const bf16* __restrict__ WoT,
    const float* __restrict__ P, const bf16* __restrict__ bob,
    float* __restrict__ outp)
{
    __shared__ bf16 Bs[2][256 * 64];   // 64 KB  Wo' chunk (double)
    __shared__ bf16 Vs[2][32 * 64];    // 8 KB   v chunk (double)
    int m0 = blockIdx.x * 32;
    int tid = threadIdx.x, wave = tid >> 6, lane = tid & 63;
    int wm = (wave >> 1) * 16, wn = (wave & 1) * 128;
    int mrow = lane & 15, quad = lane >> 4;
    int t = wm + mrow, ts = t & 7;
    int sl8 = lane >> 3, sl = lane & 7;

    float Pv[64];
    {
        const float* pr = P + (size_t)(m0 + t) * 64;
#pragma unroll
        for (int j = 0; j < 16; j++) {
            f32x4 v4 = *(const f32x4*)&pr[j * 4];
            Pv[4 * j + 0] = v4[0]; Pv[4 * j + 1] = v4[1];
            Pv[4 * j + 2] = v4[2]; Pv[4 * j + 3] = v4[3];
        }
    }

    f32x4 acc[8] = {};
    {   // prologue: stage chunk 0
        int tt = (wave << 3) + sl8;
        GLDS16(&vb[(size_t)(m0 + tt) * VN + ((sl ^ (tt & 7)) << 3)],
               &Vs[0][wave * 512]);
#pragma unroll
        for (int i = 0; i < 8; i++) {
            int n = (wave << 6) + (i << 3) + sl8;
            GLDS16(&WoT[(size_t)n * HD + ((sl ^ (n & 7)) << 3)],
                   &Bs[0][((wave << 6) + (i << 3)) << 6]);
        }
    }

    for (int c = 0; c < 32; c++) {
        __syncthreads();               // buf[c&1] resident (barrier drains vmcnt)
        if (c < 31) {
            int cc = c + 1, bb = cc & 1;
            int tt = (wave << 3) + sl8;
            GLDS16(&vb[(size_t)(m0 + tt) * VN + cc * 64 + ((sl ^ (tt & 7)) << 3)],
                   &Vs[bb][wave * 512]);
#pragma unroll
            for (int i = 0; i < 8; i++) {
                int n = (wave << 6) + (i << 3) + sl8;
                GLDS16(&WoT[(size_t)n * HD + cc * 64 + ((sl ^ (n & 7)) << 3)],
                       &Bs[bb][((wave << 6) + (i << 3)) << 6]);
            }
        }
        const bf16* Vb = Vs[c & 1];
        const bf16* Bb = Bs[c & 1];

        bf16x8 vf0 = *(const bf16x8*)&Vb[(t << 6) + ((quad ^ ts) << 3)];
        bf16x8 vf1 = *(const bf16x8*)&Vb[(t << 6) + (((quad + 4) ^ ts) << 3)];
        float v0f[8], v1f[8];
#pragma unroll
        for (int e = 0; e < 8; e++) { v0f[e] = (float)vf0[e]; v1f[e] = (float)vf1[e]; }
        bf16x8 af0, af1;
#pragma unroll
        for (int hh = 0; hh < 8; hh++) {
            float a0 = 0.f, a1 = 0.f;
#pragma unroll
            for (int gg = 0; gg < 8; gg++) {
                a0 += Pv[hh * 8 + gg] * v0f[gg];
                a1 += Pv[hh * 8 + gg] * v1f[gg];
            }
            af0[hh] = (bf16)a0; af1[hh] = (bf16)a1;
        }
#pragma unroll
        for (int nt = 0; nt < 8; nt++) {
            bf16x8 bv = *(const bf16x8*)&Bb[(wn + nt * 16 + mrow) * 64
                            + ((quad ^ (mrow & 7)) << 3)];
            acc[nt] = __builtin_amdgcn_mfma_f32_16x16x32_bf16(bv, af0, acc[nt], 0, 0, 0);
        }
#pragma unroll
        for (int nt = 0; nt < 8; nt++) {
            bf16x8 bv = *(const bf16x8*)&Bb[(wn + nt * 16 + mrow) * 64
                            + (((4 + quad) ^ (mrow & 7)) << 3)];
            acc[nt] = __builtin_amdgcn_mfma_f32_16x16x32_bf16(bv, af1, acc[nt], 0, 0, 0);
        }
    }

    int row = m0 + wm + mrow;
#pragma unroll
    for (int nt = 0; nt < 8; nt++) {
        int col = wn + nt * 16 + quad * 4;
        bf16x4 bb = *(const bf16x4*)&bob[col];
        f32x4 o;
        for (int r = 0; r < 4; r++) o[r] = acc[nt][r] + (float)bb[r];
        *(f32x4*)&outp[(size_t)row * D_ + col] = o;
    }
}

// ---------------------------------------------------------------------------
extern "C" void kernel_launch(void* const* d_in, const int* in_sizes, int n_in,
                              void* d_out, int out_size, void* d_ws, size_t ws_size,
                              hipStream_t stream)
{
    const void* x  = d_in[0];
    const void* Wq = d_in[1];
    const void* bq = d_in[2];
    const void* Wk = d_in[3];
    const void* bk = d_in[4];
    const void* Wv = d_in[5];
    const void* bv = d_in[6];
    const void* Wo = d_in[7];
    const void* bo = d_in[8];
    float* out = (float*)d_out;

    char* ws = (char*)d_ws;
    bf16*  vbuf = (bf16*)ws;                      // 16384*2048*2 = 67108864
    bf16*  WTI  = (bf16*)(ws + 67108864);         // 6144*256*2   = 3145728
    bf16*  WoT  = (bf16*)(ws + 70254592);         // 256*2048*2   = 1048576
    bf16*  xb   = (bf16*)(ws + 71303168);         // 16384*256*2  = 8388608
    bf16*  bqkv = (bf16*)(ws + 79691776);         // 6144*2       = 12288
    bf16*  bob  = (bf16*)(ws + 79704064);         // 512
    float* Pbuf = (float*)(ws + 79704576);        // 16384*64*4   = 4194304

    prep<<<6169, 256, 0, stream>>>(x, Wq, bq, Wk, bk, Wv, bv, Wo, bo,
                                   xb, WTI, WoT, bqkv, bob);
    qk_score<<<512, 512, 0, stream>>>(xb, WTI, bqkv, Pbuf);
    v_proj<<<dim3(16, 128), 256, 0, stream>>>(xb, WTI + 4096 * 256, bqkv + 4096, vbuf);
    out_fused<<<512, 256, 0, stream>>>(vbuf, WoT, Pbuf, bob, out);
}

// Round 8
// 241.370 us; speedup vs baseline: 1.4074x; 1.0957x over previous
//
#include <hip/hip_runtime.h>
#include <hip/hip_bf16.h>
#include <math.h>

typedef __bf16 bf16;
typedef __bf16 bf16x4 __attribute__((ext_vector_type(4)));
typedef __bf16 bf16x8 __attribute__((ext_vector_type(8)));
typedef float f32x4 __attribute__((ext_vector_type(4)));
typedef unsigned int u32;
typedef u32 __attribute__((address_space(1))) gu32;
typedef u32 __attribute__((address_space(3))) lu32;

#define TOK   16384
#define D_    256
#define HD    2048
#define VN    2048

#define GLDS16(g, l) __builtin_amdgcn_global_load_lds((gu32*)(g), (lu32*)(l), 16, 0, 0)
// s_waitcnt imm: vmcnt[3:0]|[15:14] | expcnt<<4 | lgkmcnt<<8
#define WAIT_VM(n)  __builtin_amdgcn_s_waitcnt(0x0F70 | (n))   // lgkm=15(no), exp=7(no), vm=n (LITERAL)
#define WAIT_LGKM0  __builtin_amdgcn_s_waitcnt(0xC07F)          // vm=63(no), exp=7(no), lgkm=0
#define BAR() do { __builtin_amdgcn_s_barrier(); __builtin_amdgcn_sched_barrier(0); } while (0)
#define SCHEDFENCE() __builtin_amdgcn_sched_barrier(0)

// ---------------------------------------------------------------------------
// prep: roles by blockIdx.x. Dtype flag computed block-locally.
//   b <  4096: convert x
//   b <  4121: biases -> bqkv (WTI-row order), bo -> bob
//   b <  5657: Wq/Wk/Wv transpose into WTI (6144 rows x 256 K):
//              q: row = (d>>3)*128 +      h*8 + (d&7)   (d-block-of-8 interleave)
//              k: row = (d>>3)*128 + 64 + h*8 + (d&7)
//              v: row = 4096 + d*8 + h                  (d-major)
//   b <  6169: Wo transpose (K permuted d-major) -> WoT
// ---------------------------------------------------------------------------
__device__ __forceinline__ void transpose_body(
    const void* __restrict__ src, bf16* __restrict__ dst, int R, int C,
    int tc, int tr, int f, int mode, float (*tile)[33])
{
    int lx = threadIdx.x & 31, ly = threadIdx.x >> 5;
    for (int i = 0; i < 4; i++) {
        int r = ly + i * 8;
        size_t idx = (size_t)(tr + r) * C + tc + lx;
        tile[r][lx] = f ? ((const float*)src)[idx] : (float)((const bf16*)src)[idx];
    }
    __syncthreads();
    for (int i = 0; i < 4; i++) {
        int r = ly + i * 8;
        int k = tr + lx;                     // source row = K index
        int n = tc + r;                      // source col = output row
        size_t di;
        if (mode == 1)
            di = (size_t)n * 2048 + ((k & 255) << 3) + (k >> 8);
        else if (mode == 2)
            di = (size_t)(4096 + ((n & 255) << 3) + (n >> 8)) * 256 + k;
        else if (mode == 3)
            di = (size_t)((((n & 255) >> 3) << 7) + ((n >> 8) << 3) + (n & 7)) * 256 + k;
        else if (mode == 4)
            di = (size_t)((((n & 255) >> 3) << 7) + 64 + ((n >> 8) << 3) + (n & 7)) * 256 + k;
        else
            di = (size_t)n * R + k;
        dst[di] = (bf16)tile[lx][r];
    }
}

__global__ __launch_bounds__(256) void prep(
    const void* __restrict__ x,
    const void* __restrict__ Wq, const void* __restrict__ bq,
    const void* __restrict__ Wk, const void* __restrict__ bk,
    const void* __restrict__ Wv, const void* __restrict__ bv,
    const void* __restrict__ Wo, const void* __restrict__ bo,
    bf16* __restrict__ xb, bf16* __restrict__ WTI, bf16* __restrict__ WoT,
    bf16* __restrict__ bqkv, bf16* __restrict__ bob)
{
    __shared__ float tile[32][33];
    __shared__ int sflag;
    int tid = threadIdx.x;
    if (tid == 0) sflag = 0;
    __syncthreads();
    {
        float v = fabsf((float)((const bf16*)x)[2 * tid]);
        if (!(v < 1e4f)) sflag = 1;   // benign race, all writers store 1
    }
    __syncthreads();
    int f = sflag;
    int b = blockIdx.x;

    if (b < 4096) {                               // convert x
        int i = b * 256 + tid;
        bf16x4 o;
        if (f) { f32x4 v = ((const f32x4*)x)[i]; for (int e = 0; e < 4; e++) o[e] = (bf16)v[e]; }
        else   { o = ((const bf16x4*)x)[i]; }
        ((bf16x4*)xb)[i] = o;
    } else if (b < 4121) {                        // biases (WTI-row order)
        int i = (b - 4096) * 256 + tid;
        if (i < 6400) {
            const void* src; bf16* dst = bqkv; int off, woff;
            if (i < 2048) {
                src = bq; off = i;
                int d = off & 255, h = off >> 8;
                woff = ((d >> 3) << 7) + (h << 3) + (d & 7);
            } else if (i < 4096) {
                src = bk; off = i - 2048;
                int d = off & 255, h = off >> 8;
                woff = ((d >> 3) << 7) + 64 + (h << 3) + (d & 7);
            } else if (i < 6144) {
                src = bv; off = i - 4096;
                woff = 4096 + ((off & 255) << 3) + (off >> 8);
            } else {
                src = bo; dst = bob; off = i - 6144; woff = off;
            }
            float v = f ? ((const float*)src)[off] : (float)((const bf16*)src)[off];
            dst[woff] = (bf16)v;
        }
        __syncthreads();                          // match transpose barrier count
    } else if (b < 5657) {                        // Wq/Wk/Wv -> WTI
        int idx = b - 4121;                       // 0..1535
        int tx = idx & 63, rest = idx >> 6;
        int ty = rest & 7, tz = rest >> 3;
        const void* src = (tz == 0) ? Wq : (tz == 1) ? Wk : Wv;
        int mode = (tz == 0) ? 3 : (tz == 1) ? 4 : 2;
        transpose_body(src, WTI, 256, 2048, tx * 32, ty * 32, f, mode, tile);
    } else {                                      // Wo -> WoT (K d-major)
        int idx = b - 5657;                       // 0..511
        int tx = idx & 7, ty = idx >> 3;
        transpose_body(Wo, WoT, 2048, 256, tx * 32, ty * 32, f, 1, tile);
    }
}

// ---------------------------------------------------------------------------
// Kernel 1: v = x @ Wv + bv  (d-major cols). Verified kernel, unchanged.
// ---------------------------------------------------------------------------
__global__ __launch_bounds__(256) void v_proj(
    const bf16* __restrict__ X, const bf16* __restrict__ WT,
    const bf16* __restrict__ bI, bf16* __restrict__ vout)
{
    __shared__ char smem[36864];               // union: As+Bs (32K) / epi (36K)
    bf16* As = (bf16*)smem;                    // 128*64
    bf16* Bs = (bf16*)(smem + 16384);          // 128*64
    int m0 = blockIdx.y * 128, n0 = blockIdx.x * 128;
    int tid = threadIdx.x, wave = tid >> 6, lane = tid & 63;
    int wm = (wave >> 1) * 64, wn = (wave & 1) * 64;
    int mrow = lane & 15, quad = lane >> 4;
    int lrow8 = lane >> 3, lslot = lane & 7;

    f32x4 acc[4][4] = {};
    for (int k0 = 0; k0 < D_; k0 += 64) {
        __syncthreads();
        for (int i = 0; i < 4; i++) {
            int rbase = wave * 32 + i * 8;
            int row = rbase + lrow8;
            int gc = lslot ^ (row & 7);
            GLDS16(&X[(size_t)(m0 + row) * D_ + k0 + gc * 8], &As[rbase * 64]);
            GLDS16(&WT[(size_t)(n0 + row) * D_ + k0 + gc * 8], &Bs[rbase * 64]);
        }
        __syncthreads();
        for (int kk = 0; kk < 64; kk += 32) {
            int slot = (((kk >> 3) + quad) ^ (mrow & 7)) * 8;
            bf16x8 af[4], bfv[4];
            for (int mt = 0; mt < 4; mt++)
                af[mt] = *(const bf16x8*)&As[(wm + mt * 16 + mrow) * 64 + slot];
            for (int nt = 0; nt < 4; nt++)
                bfv[nt] = *(const bf16x8*)&Bs[(wn + nt * 16 + mrow) * 64 + slot];
            for (int mt = 0; mt < 4; mt++)
                for (int nt = 0; nt < 4; nt++)
                    acc[mt][nt] = __builtin_amdgcn_mfma_f32_16x16x32_bf16(
                        bfv[nt], af[mt], acc[mt][nt], 0, 0, 0);
        }
    }

    __syncthreads();
    bf16* ep = (bf16*)smem + wave * (64 * 72);
    for (int mt = 0; mt < 4; mt++) {
        for (int nt = 0; nt < 4; nt++) {
            int col = n0 + wn + nt * 16 + quad * 4;
            bf16x4 bb = *(const bf16x4*)&bI[col];
            bf16x4 o;
            for (int r = 0; r < 4; r++) o[r] = (bf16)(acc[mt][nt][r] + (float)bb[r]);
            *(bf16x4*)&ep[(mt * 16 + mrow) * 72 + nt * 16 + quad * 4] = o;
        }
    }
    __syncthreads();
    for (int i = 0; i < 8; i++) {
        int r = i * 8 + (lane >> 3);
        int cb = (lane & 7) * 8;
        bf16x8 val = *(const bf16x8*)&ep[r * 72 + cb];
        *(bf16x8*)&vout[(size_t)(m0 + wm + r) * VN + n0 + wn + cb] = val;
    }
}

// ---------------------------------------------------------------------------
// Kernel 2: q/k projection + per-token 8x8 scores + softmax -> P.  v4:
//  - wave owns ALL 64 tokens (A in regs: areg[4][8], 128 VGPR) x its own 16
//    cols -> each B ds_read_b128 feeds 4 MFMA (was 1): LDS traffic /2
//  - B is wave-PRIVATE: per-wave 2x8KB LDS ring, counted per-wave vmcnt(8),
//    NO barriers for B; stage issued right after prev buffer's reads retire
//  - iteration = one d-block of 8 (128 cols: q 64 + k 64) -> score every
//    iter from single 17KB qkh (stride 136 elems: epi 2-way, score 0-way,
//    bv 2-way bank conflicts - all free)
//  - 2 raw barriers/iter (qkh publish + reuse); DMA stays in flight across
// ---------------------------------------------------------------------------
__global__ __launch_bounds__(512, 2) void qk_score(
    const bf16* __restrict__ X, const bf16* __restrict__ WTI,
    const bf16* __restrict__ bI, float* __restrict__ P)
{
    __shared__ bf16 Ws[8][2][16 * 256];   // 128 KB: per-wave double-buffered B
    __shared__ bf16 qkh[64 * 136];        // 17 KB: [t][qk*64+h*8+dd], pad to 136
    int tid = threadIdx.x, wave = tid >> 6, lane = tid & 63;
    int mrow = lane & 15, quad = lane >> 4;
    int h = lane >> 3, g = lane & 7;
    int t0 = blockIdx.x * 64;
    bf16* wsbase = &Ws[0][0][0];

    // ---- prologue: x-tile 64x256 -> first 32KB of Ws (cooperative) ----
#pragma unroll
    for (int i = 0; i < 4; i++) {
        int row = (i * 8 + wave) * 2 + (lane >> 5);
        int sl = lane & 31;
        int gc = (sl & 24) | ((sl & 7) ^ (row & 7));
        GLDS16(&X[(size_t)(t0 + row) * 256 + gc * 8], &wsbase[(i * 8 + wave) * 512]);
    }
    WAIT_VM(0);
    BAR();
    bf16x8 areg[4][8];                    // all 64 tokens, K=256
#pragma unroll
    for (int mt = 0; mt < 4; mt++)
#pragma unroll
        for (int ks = 0; ks < 8; ks++) {
            int arow = mt * 16 + mrow;
            int sl = ks * 4 + quad;
            int ph = (sl & 24) | ((sl & 7) ^ (arow & 7));
            areg[mt][ks] = *(const bf16x8*)&wsbase[arow * 256 + ph * 8];
        }
    WAIT_LGKM0;                           // A lifts retired before Ws reuse
    BAR();

    bf16* wsw = &Ws[wave][0][0];          // this wave's 2x4096-elem ring
    const bf16* wsrc = WTI + (size_t)(wave * 16) * 256;
#define QK_STAGE(IT, BUF) {                                                    \
        const bf16* s_ = wsrc + (size_t)(IT) * 32768;                          \
        bf16* d_ = wsw + (BUF) * 4096;                                         \
        _Pragma("unroll")                                                      \
        for (int j = 0; j < 8; j++) {                                          \
            int row = j * 2 + (lane >> 5);                                     \
            int sl = lane & 31;                                                \
            int gc = (sl & 24) | ((sl & 7) ^ (row & 7));                       \
            GLDS16(&s_[(size_t)row * 256 + gc * 8], &d_[j * 512]);             \
        } }
    QK_STAGE(0, 0)
    QK_STAGE(1, 1)

    float S[8] = {};

    for (int it = 0; it < 32; it++) {
        if (it == 31) { WAIT_VM(0); } else { WAIT_VM(8); }   // buf it&1 resident
        const bf16* wb = wsw + (it & 1) * 4096;
        bf16x8 bvv[8];
#pragma unroll
        for (int ks = 0; ks < 8; ks++) {
            int sl = ks * 4 + quad;
            int ph = (sl & 24) | ((sl & 7) ^ (mrow & 7));
            bvv[ks] = *(const bf16x8*)&wb[mrow * 256 + ph * 8];
        }
        WAIT_LGKM0;                        // bvv in regs -> buffer free for DMA
        SCHEDFENCE();
        if (it < 30) QK_STAGE(it + 2, it & 1)

        f32x4 acc[4] = {};
#pragma unroll
        for (int ks = 0; ks < 8; ks++)
#pragma unroll
            for (int mt = 0; mt < 4; mt++)
                acc[mt] = __builtin_amdgcn_mfma_f32_16x16x32_bf16(
                    bvv[ks], areg[mt][ks], acc[mt], 0, 0, 0);

        // epilogue -> qkh: token t = mt*16+mrow, col-idx = wave*16+quad*4+r
        bf16x4 bb = *(const bf16x4*)&bI[it * 128 + wave * 16 + quad * 4];
#pragma unroll
        for (int mt = 0; mt < 4; mt++) {
            int t = mt * 16 + mrow;
            bf16x4 o;
#pragma unroll
            for (int r = 0; r < 4; r++) o[r] = (bf16)(acc[mt][r] + (float)bb[r]);
            *(bf16x4*)&qkh[t * 136 + wave * 16 + quad * 4] = o;
        }
        WAIT_LGKM0;                        // epi writes committed
        BAR();                             // qkh(it) published to all waves

        // score accumulate: wave owns tokens wave*8..+7; reads are broadcast
#pragma unroll
        for (int u = 0; u < 8; u++) {
            int t = wave * 8 + u;
            bf16x8 qv = *(const bf16x8*)&qkh[t * 136 + h * 8];
            bf16x8 kv = *(const bf16x8*)&qkh[t * 136 + 64 + g * 8];
            float a = 0.f;
#pragma unroll
            for (int e = 0; e < 8; e++) a += (float)qv[e] * (float)kv[e];
            S[u] += a;
        }
        WAIT_LGKM0;                        // score reads retired
        BAR();                             // before next iter's epi rewrites qkh
    }
#undef QK_STAGE

    // ---- softmax + P write (wave owns tokens wave*8..+7) ----
#pragma unroll
    for (int u = 0; u < 8; u++) {
        int t = t0 + wave * 8 + u;
        float sc = S[u] * 0.0625f;
        float m = sc;
        for (int off = 1; off < 8; off <<= 1) m = fmaxf(m, __shfl_xor(m, off, 8));
        float p = __expf(sc - m);
        float sum = p;
        for (int off = 1; off < 8; off <<= 1) sum += __shfl_xor(sum, off, 8);
        P[(size_t)t * 64 + lane] = p / sum;
    }
}

// ---------------------------------------------------------------------------
// Kernel 3: out = (P @ v) @ Wo' + bo, attnout never in LDS or HBM.
// (Verified kernel, unchanged.)
// ---------------------------------------------------------------------------
__global__ __launch_bounds__(256) void out_fused(
    const bf16* __restrict__ vb, const bf16* __restrict__ WoT,
    const float* __restrict__ P, const bf16* __restrict__ bob,
    float* __restrict__ outp)
{
    __shared__ bf16 Bs[2][256 * 64];   // 64 KB  Wo' chunk (double)
    __shared__ bf16 Vs[2][32 * 64];    // 8 KB   v chunk (double)
    int m0 = blockIdx.x * 32;
    int tid = threadIdx.x, wave = tid >> 6, lane = tid & 63;
    int wm = (wave >> 1) * 16, wn = (wave & 1) * 128;
    int mrow = lane & 15, quad = lane >> 4;
    int t = wm + mrow, ts = t & 7;
    int sl8 = lane >> 3, sl = lane & 7;

    float Pv[64];
    {
        const float* pr = P + (size_t)(m0 + t) * 64;
#pragma unroll
        for (int j = 0; j < 16; j++) {
            f32x4 v4 = *(const f32x4*)&pr[j * 4];
            Pv[4 * j + 0] = v4[0]; Pv[4 * j + 1] = v4[1];
            Pv[4 * j + 2] = v4[2]; Pv[4 * j + 3] = v4[3];
        }
    }

    f32x4 acc[8] = {};
    {   // prologue: stage chunk 0
        int tt = (wave << 3) + sl8;
        GLDS16(&vb[(size_t)(m0 + tt) * VN + ((sl ^ (tt & 7)) << 3)],
               &Vs[0][wave * 512]);
#pragma unroll
        for (int i = 0; i < 8; i++) {
            int n = (wave << 6) + (i << 3) + sl8;
            GLDS16(&WoT[(size_t)n * HD + ((sl ^ (n & 7)) << 3)],
                   &Bs[0][((wave << 6) + (i << 3)) << 6]);
        }
    }

    for (int c = 0; c < 32; c++) {
        __syncthreads();               // buf[c&1] resident (barrier drains vmcnt)
        if (c < 31) {
            int cc = c + 1, bb = cc & 1;
            int tt = (wave << 3) + sl8;
            GLDS16(&vb[(size_t)(m0 + tt) * VN + cc * 64 + ((sl ^ (tt & 7)) << 3)],
                   &Vs[bb][wave * 512]);
#pragma unroll
            for (int i = 0; i < 8; i++) {
                int n = (wave << 6) + (i << 3) + sl8;
                GLDS16(&WoT[(size_t)n * HD + cc * 64 + ((sl ^ (n & 7)) << 3)],
                       &Bs[bb][((wave << 6) + (i << 3)) << 6]);
            }
        }
        const bf16* Vb = Vs[c & 1];
        const bf16* Bb = Bs[c & 1];

        bf16x8 vf0 = *(const bf16x8*)&Vb[(t << 6) + ((quad ^ ts) << 3)];
        bf16x8 vf1 = *(const bf16x8*)&Vb[(t << 6) + (((quad + 4) ^ ts) << 3)];
        float v0f[8], v1f[8];
#pragma unroll
        for (int e = 0; e < 8; e++) { v0f[e] = (float)vf0[e]; v1f[e] = (float)vf1[e]; }
        bf16x8 af0, af1;
#pragma unroll
        for (int hh = 0; hh < 8; hh++) {
            float a0 = 0.f, a1 = 0.f;
#pragma unroll
            for (int gg = 0; gg < 8; gg++) {
                a0 += Pv[hh * 8 + gg] * v0f[gg];
                a1 += Pv[hh * 8 + gg] * v1f[gg];
            }
            af0[hh] = (bf16)a0; af1[hh] = (bf16)a1;
        }
#pragma unroll
        for (int nt = 0; nt < 8; nt++) {
            bf16x8 bv = *(const bf16x8*)&Bb[(wn + nt * 16 + mrow) * 64
                            + ((quad ^ (mrow & 7)) << 3)];
            acc[nt] = __builtin_amdgcn_mfma_f32_16x16x32_bf16(bv, af0, acc[nt], 0, 0, 0);
        }
#pragma unroll
        for (int nt = 0; nt < 8; nt++) {
            bf16x8 bv = *(const bf16x8*)&Bb[(wn + nt * 16 + mrow) * 64
                            + (((4 + quad) ^ (mrow & 7)) << 3)];
            acc[nt] = __builtin_amdgcn_mfma_f32_16x16x32_bf16(bv, af1, acc[nt], 0, 0, 0);
        }
    }

    int row = m0 + wm + mrow;
#pragma unroll
    for (int nt = 0; nt < 8; nt++) {
        int col = wn + nt * 16 + quad * 4;
        bf16x4 bb = *(const bf16x4*)&bob[col];
        f32x4 o;
        for (int r = 0; r < 4; r++) o[r] = acc[nt][r] + (float)bb[r];
        *(f32x4*)&outp[(size_t)row * D_ + col] = o;
    }
}

// ---------------------------------------------------------------------------
extern "C" void kernel_launch(void* const* d_in, const int* in_sizes, int n_in,
                              void* d_out, int out_size, void* d_ws, size_t ws_size,
                              hipStream_t stream)
{
    const void* x  = d_in[0];
    const void* Wq = d_in[1];
    const void* bq = d_in[2];
    const void* Wk = d_in[3];
    const void* bk = d_in[4];
    const void* Wv = d_in[5];
    const void* bv = d_in[6];
    const void* Wo = d_in[7];
    const void* bo = d_in[8];
    float* out = (float*)d_out;

    char* ws = (char*)d_ws;
    bf16*  vbuf = (bf16*)ws;                      // 16384*2048*2 = 67108864
    bf16*  WTI  = (bf16*)(ws + 67108864);         // 6144*256*2   = 3145728
    bf16*  WoT  = (bf16*)(ws + 70254592);         // 256*2048*2   = 1048576
    bf16*  xb   = (bf16*)(ws + 71303168);         // 16384*256*2  = 8388608
    bf16*  bqkv = (bf16*)(ws + 79691776);         // 6144*2       = 12288
    bf16*  bob  = (bf16*)(ws + 79704064);         // 512
    float* Pbuf = (float*)(ws + 79704576);        // 16384*64*4   = 4194304

    prep<<<6169, 256, 0, stream>>>(x, Wq, bq, Wk, bk, Wv, bv, Wo, bo,
                                   xb, WTI, WoT, bqkv, bob);
    qk_score<<<256, 512, 0, stream>>>(xb, WTI, bqkv, Pbuf);
    v_proj<<<dim3(16, 128), 256, 0, stream>>>(xb, WTI + 4096 * 256, bqkv + 4096, vbuf);
    out_fused<<<512, 256, 0, stream>>>(vbuf, WoT, Pbuf, bob, out);
}